// Round 23
// baseline (4983.150 us; speedup 1.0000x reference)
//
#include <hip/hip_runtime.h>

#define BB 64
#define SS 2048
#define II 128
#define HH 256
#define OO 128

typedef _Float16 h2_t  __attribute__((ext_vector_type(2)));
typedef _Float16 half8 __attribute__((ext_vector_type(8)));
typedef float    f32x4 __attribute__((ext_vector_type(4)));

// ---------------------------------------------------------------------------
// Prep: combine biases, write the fp32 SWIZZLED scan weights wswf, and pack
// W_fc / W_ih into MFMA A-fragment order (HW-verified in v14/v15).
//   wswf float4 slot s = w*2048 + (o*8 + i)*64 + l holds
//   W_hh[j = w*32 + (l&7)*4 + o][k = (l>>3)*32 + i*4 .. +3]
//   -> per-step scan loads are lane-consecutive 16B chunks (coalesced).
// ---------------------------------------------------------------------------
__global__ void prep_kernel(const float* __restrict__ W_ih, const float* __restrict__ b_ih,
                            const float* __restrict__ b_hh, const float* __restrict__ W_fc,
                            float* __restrict__ biasc, float* __restrict__ wswf,
                            unsigned* __restrict__ wfcp, unsigned* __restrict__ wihp,
                            const float* __restrict__ W_hh) {
    int idx = blockIdx.x * 256 + threadIdx.x;      // grid 256*256 = 65536
    if (idx < HH * HH) {            // fp32 swizzled scan weights (65536 f)
        int d = idx & 3;
        int s = idx >> 2;           // float4 slot
        int l = s & 63;
        int rem = s >> 6;           // 0..255
        int i = rem & 7;
        int o = (rem >> 3) & 3;
        int w = rem >> 5;
        int j = w * 32 + (l & 7) * 4 + o;
        int k = (l >> 3) * 32 + i * 4 + d;
        wswf[idx] = W_hh[j * HH + k];
    }
    if (idx < 8 * 8 * 64 * 4) {     // wfcp: W_fc MFMA fragments (16384 dwords)
        int d    = idx & 3;
        int slot = idx >> 2;
        int l    = slot & 63;
        int kt   = (slot >> 6) & 7;
        int jt   = slot >> 9;
        int j    = jt * 16 + (l & 15);
        int k0   = kt * 32 + (l >> 4) * 8 + d * 2;
        union { h2_t h; unsigned u; } pk;
        pk.h.x = (_Float16)W_fc[j * HH + k0];
        pk.h.y = (_Float16)W_fc[j * HH + k0 + 1];
        wfcp[idx] = pk.u;
    }
    if (idx < 16 * 4 * 64 * 4) {    // wihp: W_ih MFMA fragments (16384 dwords)
        int d    = idx & 3;
        int slot = idx >> 2;
        int l    = slot & 63;
        int kt   = (slot >> 6) & 3;
        int jt   = slot >> 8;
        int j    = jt * 16 + (l & 15);
        int k0   = kt * 32 + (l >> 4) * 8 + d * 2;
        union { h2_t h; unsigned u; } pk;
        pk.h.x = (_Float16)W_ih[j * II + k0];
        pk.h.y = (_Float16)W_ih[j * II + k0 + 1];
        wihp[idx] = pk.u;
    }
    if (idx < HH) biasc[idx] = b_ih[idx] + b_hh[idx];
}

// ---------------------------------------------------------------------------
// GEMM1 via MFMA f16 (HW-verified in v15): xproj = x @ W_ih^T + biasc.
// ---------------------------------------------------------------------------
__global__ __launch_bounds__(256, 4)
void gemm1_mfma(const float* __restrict__ x, const unsigned* __restrict__ wihp,
                const float* __restrict__ biasc, float* __restrict__ xproj) {
    const int tid = threadIdx.x;
    const int w   = tid >> 6;
    const int l   = tid & 63;
    const int krow = l >> 4;
    const long r  = (long)blockIdx.x * 64 + w * 16 + (l & 15);
    const float* __restrict__ xrow = x + r * II;

    f32x4 acc[16];
#pragma unroll
    for (int jt = 0; jt < 16; ++jt) acc[jt] = (f32x4){0.f, 0.f, 0.f, 0.f};

#pragma unroll
    for (int kt = 0; kt < 4; ++kt) {
        float4 h0 = *(const float4*)&xrow[kt * 32 + krow * 8];
        float4 h1 = *(const float4*)&xrow[kt * 32 + krow * 8 + 4];
        half8 bf;
        bf[0] = (_Float16)h0.x; bf[1] = (_Float16)h0.y;
        bf[2] = (_Float16)h0.z; bf[3] = (_Float16)h0.w;
        bf[4] = (_Float16)h1.x; bf[5] = (_Float16)h1.y;
        bf[6] = (_Float16)h1.z; bf[7] = (_Float16)h1.w;
#pragma unroll
        for (int jt = 0; jt < 16; ++jt) {
            half8 af = *(const half8*)&wihp[(size_t)((jt * 4 + kt) * 64 + l) * 4];
            acc[jt] = __builtin_amdgcn_mfma_f32_16x16x32_f16(af, bf, acc[jt], 0, 0, 0);
        }
    }

#pragma unroll
    for (int jt = 0; jt < 16; ++jt) {
        int j0 = jt * 16 + krow * 4;
        float4 bb = *(const float4*)&biasc[j0];
        float4 o;
        o.x = acc[jt][0] + bb.x; o.y = acc[jt][1] + bb.y;
        o.z = acc[jt][2] + bb.z; o.w = acc[jt][3] + bb.w;
        *(float4*)&xproj[r * HH + j0] = o;
    }
}

// ---------------------------------------------------------------------------
// GEMM2 via MFMA f16 (HW-verified in v14): out = hidden @ W_fc^T + b_fc.
// ---------------------------------------------------------------------------
__global__ __launch_bounds__(256, 4)
void gemm2_mfma(const float* __restrict__ hidden, const unsigned* __restrict__ wfcp,
                const float* __restrict__ b_fc, float* __restrict__ out) {
    const int tid = threadIdx.x;
    const int w   = tid >> 6;
    const int l   = tid & 63;
    const int krow = l >> 4;
    const long r  = (long)blockIdx.x * 64 + w * 16 + (l & 15);
    const float* __restrict__ hrow = hidden + r * HH;

    f32x4 acc[8];
#pragma unroll
    for (int jt = 0; jt < 8; ++jt) acc[jt] = (f32x4){0.f, 0.f, 0.f, 0.f};

#pragma unroll
    for (int kt = 0; kt < 8; ++kt) {
        float4 h0 = *(const float4*)&hrow[kt * 32 + krow * 8];
        float4 h1 = *(const float4*)&hrow[kt * 32 + krow * 8 + 4];
        half8 bf;
        bf[0] = (_Float16)h0.x; bf[1] = (_Float16)h0.y;
        bf[2] = (_Float16)h0.z; bf[3] = (_Float16)h0.w;
        bf[4] = (_Float16)h1.x; bf[5] = (_Float16)h1.y;
        bf[6] = (_Float16)h1.z; bf[7] = (_Float16)h1.w;
#pragma unroll
        for (int jt = 0; jt < 8; ++jt) {
            half8 af = *(const half8*)&wfcp[(size_t)((jt * 8 + kt) * 64 + l) * 4];
            acc[jt] = __builtin_amdgcn_mfma_f32_16x16x32_f16(af, bf, acc[jt], 0, 0, 0);
        }
    }

#pragma unroll
    for (int jt = 0; jt < 8; ++jt) {
        int j0 = jt * 16 + krow * 4;
        float4 bb = *(const float4*)&b_fc[j0];
        float4 o;
        o.x = acc[jt][0] + bb.x; o.y = acc[jt][1] + bb.y;
        o.z = acc[jt][2] + bb.z; o.w = acc[jt][3] + bb.w;
        *(float4*)&out[r * OO + j0] = o;
    }
}

// ---------------------------------------------------------------------------
// Sequential scan v16: full fp32, full-rate v_fma_f32 (the instruction sweep
// showed dot2 ~8cyc, fma_mix/pk_fma worse; v_fma_f32 is the only proven
// 2-cyc MAC on this part). v10's 4-outputs x 32-k mapping (HW-verified
// reduction): 64B/lane LDS (same pipe cost as v9), 128 fmaf on 4 chains.
// Weights stream fp32 from L2 (v9's residency-free pattern); an opaque
// pointer guard blocks the compiler from hoisting the loop-invariant loads
// into the AGPR-demotion trap (v1-v8 pathology). Full fp32 recurrence ->
// absmax should return to ~0.0039.
// ---------------------------------------------------------------------------
__global__ __attribute__((amdgpu_waves_per_eu(2, 2))) __launch_bounds__(512)
void rnn_scan(const float* __restrict__ wswf, float* __restrict__ hid) {
    const int b   = blockIdx.x;
    const int tid = threadIdx.x;
    const int w   = tid >> 6;
    const int l   = tid & 63;
    const int sl  = l & 7;         // output-quad selector
    const int q   = l >> 3;        // k-group 0..7 (32 k's each)
    const int g   = q >> 1;        // owned output slot 0..3

    const int jown = w * 32 + sl * 4 + g;    // this thread's owned output

    // 8 k-groups x 32 floats, stride 36 (144B: 16B-aligned, bank offset
    // q*4 -> the 8 broadcast addresses per b128 read cover all 32 banks)
    __shared__ __align__(16) float hbuf[2][8 * 36];

    // weight stream base: float4 slot = w*2048 + (o*8+i)*64 + l
    uintptr_t wpa = (uintptr_t)((const float4*)wswf + ((size_t)w << 11) + l);

    for (int i = tid; i < 2 * 8 * 36; i += 512) ((float*)hbuf)[i] = 0.0f;

    float* __restrict__ base = hid + (size_t)b * SS * HH;
    float xp0 = base[jown];
    float xp1 = base[HH + jown];
    __syncthreads();

#pragma unroll 1
    for (int t = 0; t < SS; ++t) {
        // opaque: compiler cannot prove the weight loads loop-invariant ->
        // they re-issue each step (L2-resident) instead of hoist+demote
        asm volatile("" : "+v"(wpa));
        const float4* __restrict__ wpm = (const float4*)wpa;

        float4 w0[8], w1[8], w2[8], w3[8];
#pragma unroll
        for (int i = 0; i < 8; ++i) {
            w0[i] = wpm[i * 64];
            w1[i] = wpm[512 + i * 64];
            w2[i] = wpm[1024 + i * 64];
            w3[i] = wpm[1536 + i * 64];
        }

        // branchless clamped xp prefetch for t+2 (t+2 row not yet written)
        const int t2 = (t + 2 < SS) ? (t + 2) : (SS - 1);
        float xp2 = base[(size_t)t2 * HH + jown];

        const float4* hb = (const float4*)&hbuf[t & 1][q * 36];
        float p0 = 0.f, p1 = 0.f, p2 = 0.f, p3 = 0.f;
#pragma unroll
        for (int i = 0; i < 8; ++i) {
            float4 hv = hb[i];
            p0 = fmaf(hv.x, w0[i].x, p0);
            p0 = fmaf(hv.y, w0[i].y, p0);
            p0 = fmaf(hv.z, w0[i].z, p0);
            p0 = fmaf(hv.w, w0[i].w, p0);
            p1 = fmaf(hv.x, w1[i].x, p1);
            p1 = fmaf(hv.y, w1[i].y, p1);
            p1 = fmaf(hv.z, w1[i].z, p1);
            p1 = fmaf(hv.w, w1[i].w, p1);
            p2 = fmaf(hv.x, w2[i].x, p2);
            p2 = fmaf(hv.y, w2[i].y, p2);
            p2 = fmaf(hv.z, w2[i].z, p2);
            p2 = fmaf(hv.w, w2[i].w, p2);
            p3 = fmaf(hv.x, w3[i].x, p3);
            p3 = fmaf(hv.y, w3[i].y, p3);
            p3 = fmaf(hv.z, w3[i].z, p3);
            p3 = fmaf(hv.w, w3[i].w, p3);
        }

        // stage A: combine q with q^1 (lane^8) for all 4 outputs
        p0 += __shfl_xor(p0, 8, 64);
        p1 += __shfl_xor(p1, 8, 64);
        p2 += __shfl_xor(p2, 8, 64);
        p3 += __shfl_xor(p3, 8, 64);

        // rotated-slot reduction over lane bits 4,5 (HW-verified in v10):
        // partner g' = g^r contributes its partial[g'^r] = partial[g]
        float s  = (g == 0) ? p0 : (g == 1) ? p1 : (g == 2) ? p2 : p3;
        float x1 = (g == 0) ? p1 : (g == 1) ? p0 : (g == 2) ? p3 : p2;
        s += __shfl_xor(x1, 16, 64);
        float x2 = (g == 0) ? p2 : (g == 1) ? p3 : (g == 2) ? p0 : p1;
        s += __shfl_xor(x2, 32, 64);
        float x3 = (g == 0) ? p3 : (g == 1) ? p2 : (g == 2) ? p1 : p0;
        s += __shfl_xor(x3, 48, 64);

        s += xp0;
        // tanh(s) = 1 - 2/(e^{2s}+1); overflow-safe without clamps
        float e  = __expf(2.0f * s);
        float hn = 1.0f - __fdividef(2.0f, e + 1.0f);

        if (!(q & 1)) {           // one writer per output
            hbuf[(t & 1) ^ 1][(jown >> 5) * 36 + (jown & 31)] = hn;
            base[(size_t)t * HH + jown] = hn;
        }
        __syncthreads();
        xp0 = xp1;
        xp1 = xp2;
    }
}

// ---------------------------------------------------------------------------
extern "C" void kernel_launch(void* const* d_in, const int* in_sizes, int n_in,
                              void* d_out, int out_size, void* d_ws, size_t ws_size,
                              hipStream_t stream) {
    const float* x    = (const float*)d_in[0];
    const float* W_ih = (const float*)d_in[1];
    const float* W_hh = (const float*)d_in[2];
    const float* b_ih = (const float*)d_in[3];
    const float* b_hh = (const float*)d_in[4];
    const float* W_fc = (const float*)d_in[5];
    const float* b_fc = (const float*)d_in[6];

    float* out_fc  = (float*)d_out;                          // [B][S][O]
    float* hidden  = (float*)d_out + (size_t)BB * SS * OO;   // [B][S][H]

    float*    biasc = (float*)d_ws;                   // [H]          256 f
    float*    wswf  = biasc + HH;                     // scan wts   65536 f
    unsigned* wfcp  = (unsigned*)(wswf + HH * HH);    // W_fc frags 16384 u32
    unsigned* wihp  = wfcp + 8 * 8 * 64 * 4;          // W_ih frags 16384 u32

    const long NR = (long)BB * SS;                    // 131072 rows

    prep_kernel<<<256, 256, 0, stream>>>(W_ih, b_ih, b_hh, W_fc,
                                         biasc, wswf, wfcp, wihp, W_hh);
    gemm1_mfma<<<NR / 64, 256, 0, stream>>>(x, wihp, biasc, hidden);
    rnn_scan<<<BB, 512, 0, stream>>>(wswf, hidden);
    gemm2_mfma<<<NR / 64, 256, 0, stream>>>(hidden, wfcp, b_fc, out_fc);
}

// Round 24
// 1354.055 us; speedup vs baseline: 3.6802x; 3.6802x over previous
//
#include <hip/hip_runtime.h>

#define BB 64
#define SS 2048
#define II 128
#define HH 256
#define OO 128

typedef _Float16 h2_t  __attribute__((ext_vector_type(2)));
typedef _Float16 half8 __attribute__((ext_vector_type(8)));
typedef float    f32x4 __attribute__((ext_vector_type(4)));

__device__ __forceinline__ h2_t u2h(unsigned u) {
    union { unsigned u; h2_t h; } c; c.u = u; return c.h;
}

#if __has_builtin(__builtin_amdgcn_fdot2)
__device__ __forceinline__ float fdot2(unsigned h, unsigned w, float acc) {
    return __builtin_amdgcn_fdot2(u2h(h), u2h(w), acc, false);
}
#else
__device__ __forceinline__ float fdot2(unsigned h, unsigned w, float acc) {
    h2_t hh = u2h(h), ww = u2h(w);
    acc = fmaf((float)hh.x, (float)ww.x, acc);
    acc = fmaf((float)hh.y, (float)ww.y, acc);
    return acc;
}
#endif

// ---------------------------------------------------------------------------
// Prep: combine biases, write swizzled scan weights wsw (v9 layout),
// pack W_fc into MFMA A-fragment order wfcp (gemm2), and pack W_ih into
// MFMA A-fragment order wihp (gemm1).
// ---------------------------------------------------------------------------
__global__ void prep_kernel(const float* __restrict__ W_ih, const float* __restrict__ b_ih,
                            const float* __restrict__ b_hh, const float* __restrict__ W_fc,
                            float* __restrict__ biasc, unsigned* __restrict__ wsw,
                            unsigned* __restrict__ wfcp, unsigned* __restrict__ wihp,
                            const float* __restrict__ W_hh) {
    int idx = blockIdx.x * 256 + threadIdx.x;      // grid 128*256 = 32768
    if (idx < HH * (HH / 2)) {      // swizzled scan weights (32768 dwords)
        int d   = idx & 3;
        int s   = idx >> 2;
        int l   = s & 63;
        int rem = s >> 6;
        int i    = rem & 7;
        int pair = (rem >> 3) & 1;
        int w    = rem >> 4;
        int j    = w * 32 + (l & 15) * 2 + pair;
        int word = (l >> 4) * 32 + i * 4 + d;      // dword index within row j
        union { h2_t h; unsigned u; } pk;
        pk.h.x = (_Float16)W_hh[j * HH + 2 * word];
        pk.h.y = (_Float16)W_hh[j * HH + 2 * word + 1];
        wsw[idx] = pk.u;
    }
    if (idx < 8 * 8 * 64 * 4) {     // wfcp: W_fc MFMA fragments (16384 dwords)
        int d    = idx & 3;
        int slot = idx >> 2;
        int l    = slot & 63;
        int kt   = (slot >> 6) & 7;
        int jt   = slot >> 9;
        int j    = jt * 16 + (l & 15);
        int k0   = kt * 32 + (l >> 4) * 8 + d * 2;
        union { h2_t h; unsigned u; } pk;
        pk.h.x = (_Float16)W_fc[j * HH + k0];
        pk.h.y = (_Float16)W_fc[j * HH + k0 + 1];
        wfcp[idx] = pk.u;
    }
    if (idx < 16 * 4 * 64 * 4) {    // wihp: W_ih MFMA fragments (16384 dwords)
        int d    = idx & 3;
        int slot = idx >> 2;
        int l    = slot & 63;
        int kt   = (slot >> 6) & 3;
        int jt   = slot >> 8;
        int j    = jt * 16 + (l & 15);
        int k0   = kt * 32 + (l >> 4) * 8 + d * 2;
        union { h2_t h; unsigned u; } pk;
        pk.h.x = (_Float16)W_ih[j * II + k0];
        pk.h.y = (_Float16)W_ih[j * II + k0 + 1];
        wihp[idx] = pk.u;
    }
    if (idx < HH) biasc[idx] = b_ih[idx] + b_hh[idx];
}

// ---------------------------------------------------------------------------
// GEMM1 via MFMA f16 (HW-verified in v15): xproj = x @ W_ih^T + biasc.
// 2048 blocks x 256 thr (4 waves); wave = 16 r's x all 256 j (16 j-tiles).
// ---------------------------------------------------------------------------
__global__ __launch_bounds__(256, 4)
void gemm1_mfma(const float* __restrict__ x, const unsigned* __restrict__ wihp,
                const float* __restrict__ biasc, float* __restrict__ xproj) {
    const int tid = threadIdx.x;
    const int w   = tid >> 6;
    const int l   = tid & 63;
    const int krow = l >> 4;
    const long r  = (long)blockIdx.x * 64 + w * 16 + (l & 15);
    const float* __restrict__ xrow = x + r * II;

    f32x4 acc[16];
#pragma unroll
    for (int jt = 0; jt < 16; ++jt) acc[jt] = (f32x4){0.f, 0.f, 0.f, 0.f};

#pragma unroll
    for (int kt = 0; kt < 4; ++kt) {
        float4 h0 = *(const float4*)&xrow[kt * 32 + krow * 8];
        float4 h1 = *(const float4*)&xrow[kt * 32 + krow * 8 + 4];
        half8 bf;
        bf[0] = (_Float16)h0.x; bf[1] = (_Float16)h0.y;
        bf[2] = (_Float16)h0.z; bf[3] = (_Float16)h0.w;
        bf[4] = (_Float16)h1.x; bf[5] = (_Float16)h1.y;
        bf[6] = (_Float16)h1.z; bf[7] = (_Float16)h1.w;
#pragma unroll
        for (int jt = 0; jt < 16; ++jt) {
            half8 af = *(const half8*)&wihp[(size_t)((jt * 4 + kt) * 64 + l) * 4];
            acc[jt] = __builtin_amdgcn_mfma_f32_16x16x32_f16(af, bf, acc[jt], 0, 0, 0);
        }
    }

#pragma unroll
    for (int jt = 0; jt < 16; ++jt) {
        int j0 = jt * 16 + krow * 4;
        float4 bb = *(const float4*)&biasc[j0];
        float4 o;
        o.x = acc[jt][0] + bb.x; o.y = acc[jt][1] + bb.y;
        o.z = acc[jt][2] + bb.z; o.w = acc[jt][3] + bb.w;
        *(float4*)&xproj[r * HH + j0] = o;
    }
}

// ---------------------------------------------------------------------------
// GEMM2 via MFMA f16 (HW-verified in v14): out = hidden @ W_fc^T + b_fc.
// ---------------------------------------------------------------------------
__global__ __launch_bounds__(256, 4)
void gemm2_mfma(const float* __restrict__ hidden, const unsigned* __restrict__ wfcp,
                const float* __restrict__ b_fc, float* __restrict__ out) {
    const int tid = threadIdx.x;
    const int w   = tid >> 6;
    const int l   = tid & 63;
    const int krow = l >> 4;
    const long r  = (long)blockIdx.x * 64 + w * 16 + (l & 15);
    const float* __restrict__ hrow = hidden + r * HH;

    f32x4 acc[8];
#pragma unroll
    for (int jt = 0; jt < 8; ++jt) acc[jt] = (f32x4){0.f, 0.f, 0.f, 0.f};

#pragma unroll
    for (int kt = 0; kt < 8; ++kt) {
        float4 h0 = *(const float4*)&hrow[kt * 32 + krow * 8];
        float4 h1 = *(const float4*)&hrow[kt * 32 + krow * 8 + 4];
        half8 bf;
        bf[0] = (_Float16)h0.x; bf[1] = (_Float16)h0.y;
        bf[2] = (_Float16)h0.z; bf[3] = (_Float16)h0.w;
        bf[4] = (_Float16)h1.x; bf[5] = (_Float16)h1.y;
        bf[6] = (_Float16)h1.z; bf[7] = (_Float16)h1.w;
#pragma unroll
        for (int jt = 0; jt < 8; ++jt) {
            half8 af = *(const half8*)&wfcp[(size_t)((jt * 8 + kt) * 64 + l) * 4];
            acc[jt] = __builtin_amdgcn_mfma_f32_16x16x32_f16(af, bf, acc[jt], 0, 0, 0);
        }
    }

#pragma unroll
    for (int jt = 0; jt < 8; ++jt) {
        int j0 = jt * 16 + krow * 4;
        float4 bb = *(const float4*)&b_fc[j0];
        float4 o;
        o.x = acc[jt][0] + bb.x; o.y = acc[jt][1] + bb.y;
        o.z = acc[jt][2] + bb.z; o.w = acc[jt][3] + bb.w;
        *(float4*)&out[r * OO + j0] = o;
    }
}

// ---------------------------------------------------------------------------
// Sequential scan v9 (best measured: 1252-1257 us across three runs).
// 64 blocks x 512 threads, f16 weights stream from L2 (swizzled,
// coalesced), double-buffered f16 h in LDS, butterfly shfl_xor(16,32)
// reduce, one barrier per step. MAC = builtin fdot2 (the v11-v16 sweep
// measured: dot2 930 < pk_fma 1116 < fma_mix 1479 VALU-cyc/SIMD/step;
// fp32-fma + fp32-stream latency-bound at 4x worse).
// ---------------------------------------------------------------------------
__global__ __attribute__((amdgpu_waves_per_eu(2, 2))) __launch_bounds__(512)
void rnn_scan(const unsigned* __restrict__ wsw, float* __restrict__ hid) {
    const int b   = blockIdx.x;
    const int tid = threadIdx.x;
    const int w   = tid >> 6;
    const int l   = tid & 63;
    const int sl  = l & 15;
    const int q   = l >> 4;

    const int j0 = w * 32 + sl * 2;      // two outputs j0, j0+1

    __shared__ __align__(16) unsigned h16[2][4 * 36];

    // per-thread weight stream base: lane-consecutive 16B chunks
    const uint4* __restrict__ wp = (const uint4*)wsw + ((size_t)w << 10) + l;

    for (int i = tid; i < 2 * 4 * 36; i += 512) ((unsigned*)h16)[i] = 0u;

    float* __restrict__ base = hid + (size_t)b * SS * HH;
    float2 xp0 = *(const float2*)&base[j0];
    float2 xp1 = *(const float2*)&base[HH + j0];
    __syncthreads();

#pragma unroll 1
    for (int t = 0; t < SS; ++t) {
        // weight stream for this step (L2-resident, coalesced)
        uint4 wA[8], wB[8];
#pragma unroll
        for (int i = 0; i < 8; ++i) {
            wA[i] = wp[i * 64];
            wB[i] = wp[(8 + i) * 64];
        }

        // prefetch xproj for t+2 (read precedes the overwrite at t)
        float2 xp2 = make_float2(0.f, 0.f);
        if (t + 2 < SS) xp2 = *(const float2*)&base[(size_t)(t + 2) * HH + j0];

        const uint4* hb = (const uint4*)&h16[t & 1][q * 36];
        float aA0 = 0.f, aA1 = 0.f, aB0 = 0.f, aB1 = 0.f;
#pragma unroll
        for (int i = 0; i < 8; ++i) {
            uint4 hv = hb[i];
            aA0 = fdot2(hv.x, wA[i].x, aA0);
            aA1 = fdot2(hv.y, wA[i].y, aA1);
            aA0 = fdot2(hv.z, wA[i].z, aA0);
            aA1 = fdot2(hv.w, wA[i].w, aA1);
            aB0 = fdot2(hv.x, wB[i].x, aB0);
            aB1 = fdot2(hv.y, wB[i].y, aB1);
            aB0 = fdot2(hv.z, wB[i].z, aB0);
            aB1 = fdot2(hv.w, wB[i].w, aB1);
        }
        float sA = aA0 + aA1;
        float sB = aB0 + aB1;
        // butterfly over the 4 k-quarters (lanes sl, sl+16, sl+32, sl+48)
        sA += __shfl_xor(sA, 16, 64);
        sA += __shfl_xor(sA, 32, 64);
        sB += __shfl_xor(sB, 16, 64);
        sB += __shfl_xor(sB, 32, 64);

        float s0 = xp0.x + sA;
        float s1 = xp0.y + sB;
        // tanh(s) = 1 - 2/(e^{2s}+1); overflow-safe without clamps
        float e0  = __expf(2.0f * s0);
        float e1  = __expf(2.0f * s1);
        float hn0 = 1.0f - __fdividef(2.0f, e0 + 1.0f);
        float hn1 = 1.0f - __fdividef(2.0f, e1 + 1.0f);

        if (q == 0) {
            union { h2_t h; unsigned u; } pk;
            pk.h.x = (_Float16)hn0;
            pk.h.y = (_Float16)hn1;
            const int W = j0 >> 1;
            h16[(t & 1) ^ 1][(W >> 5) * 36 + (W & 31)] = pk.u;
            *(float2*)&base[(size_t)t * HH + j0] = make_float2(hn0, hn1);
        }
        __syncthreads();
        xp0 = xp1;
        xp1 = xp2;
    }
}

// ---------------------------------------------------------------------------
extern "C" void kernel_launch(void* const* d_in, const int* in_sizes, int n_in,
                              void* d_out, int out_size, void* d_ws, size_t ws_size,
                              hipStream_t stream) {
    const float* x    = (const float*)d_in[0];
    const float* W_ih = (const float*)d_in[1];
    const float* W_hh = (const float*)d_in[2];
    const float* b_ih = (const float*)d_in[3];
    const float* b_hh = (const float*)d_in[4];
    const float* W_fc = (const float*)d_in[5];
    const float* b_fc = (const float*)d_in[6];

    float* out_fc  = (float*)d_out;                          // [B][S][O]
    float* hidden  = (float*)d_out + (size_t)BB * SS * OO;   // [B][S][H]

    float*    biasc = (float*)d_ws;                   // [H]        256 f
    unsigned* wsw   = (unsigned*)(biasc + HH);        // scan wts 32768 u32
    unsigned* wfcp  = wsw + HH * (HH / 2);            // W_fc frags 16384 u32
    unsigned* wihp  = wfcp + 8 * 8 * 64 * 4;          // W_ih frags 16384 u32

    const long NR = (long)BB * SS;                    // 131072 rows

    prep_kernel<<<128, 256, 0, stream>>>(W_ih, b_ih, b_hh, W_fc,
                                         biasc, wsw, wfcp, wihp, W_hh);
    gemm1_mfma<<<NR / 64, 256, 0, stream>>>(x, wihp, biasc, hidden);
    rnn_scan<<<BB, 512, 0, stream>>>(wsw, hidden);
    gemm2_mfma<<<NR / 64, 256, 0, stream>>>(hidden, wfcp, b_fc, out_fc);
}